// Round 13
// baseline (189.609 us; speedup 1.0000x reference)
//
#include <hip/hip_runtime.h>

#define N_NODES 100000
#define N_EDGES 1600000
#define DIM 128
#define ACT 512
#define NG 64
#define CHUNK 128
#define NBUK 782            // ceil(N_NODES/CHUNK)
#define NBUK2 (2 * NBUK)
#define EB 4096             // edges per partition block (single-round, 4 blocks/CU)
#define NBLK_E 391          // ceil(N_EDGES/EB)
#define EPT 8               // edges per thread in bfill (EB/512)
#define UP 136              // bf16 row pitch for uT/cbf (16B-aligned rows)
#define ZP 132              // fp32 ctile pitch (bank-spread, b128-aligned)
#define NPART 32            // zred partial reducers per output
#define CAPE 2688           // per-bucket edata capacity (mean 2048, sd ~45 -> 14 sigma)
#define ZRB 25              // buckets per zred1 partial (32*25 >= 782)
#define GRID_A 768          // aggz persistent grid: 3 blocks/CU x 256 CU

typedef __attribute__((ext_vector_type(8))) short bf16x8;
typedef __attribute__((ext_vector_type(4))) float f32x4;

__device__ __forceinline__ unsigned short f2bf(float f) {
    union { float f; unsigned int i; } v;
    v.f = f;
    unsigned int i = v.i;
    i += 0x7fffu + ((i >> 16) & 1u);   // RNE
    return (unsigned short)(i >> 16);
}
__device__ __forceinline__ float bflo(unsigned int u) {
    union { unsigned int i; float f; } v;
    v.i = u << 16;
    return v.f;
}
__device__ __forceinline__ float bfhi(unsigned int u) {
    union { unsigned int i; float f; } v;
    v.i = u & 0xffff0000u;
    return v.f;
}

// ---------------- cursor zero ----------------

__global__ __launch_bounds__(1024) void k_zero(int* __restrict__ cur) {
    int i = blockIdx.x * 1024 + threadIdx.x;
    if (i < NBUK2) cur[i] = 0;
}

// ---------------- bucket partition via atomic segment claiming ----------------
// Side-split: blocks [0,NBLK_E) sort side D, [NBLK_E,2*NBLK_E) sort side S.
// 512 threads, EB=4096 -> ~31KB LDS, 4 blocks/CU, 782 blocks = single round.
__global__ __launch_bounds__(512, 8) void k_bfill(const int* __restrict__ src,
                                                  const int* __restrict__ dst,
                                                  const int* __restrict__ batch,
                                                  int* __restrict__ cur_d,
                                                  int* __restrict__ cur_s,
                                                  int* __restrict__ edata_d,
                                                  int* __restrict__ edata_s) {
    __shared__ int gbase[NBUK];
    __shared__ int lofs[NBUK];
    __shared__ int stage[EB];
    __shared__ unsigned short bkt[EB];
    __shared__ int stmp[8];
    int t = threadIdx.x;
    int blk = blockIdx.x;
    int sideS = (blk >= NBLK_E) ? 1 : 0;
    int pblk = sideS ? blk - NBLK_E : blk;
    int e0 = pblk * EB;
    int e1 = min(e0 + EB, N_EDGES);
    int ne = e1 - e0;
    int my0 = e0 + t * EPT;

    const int* keyp = sideS ? src : dst;
    const int* othp = sideS ? dst : src;
    int* cur = sideS ? cur_s : cur_d;
    int* edata = sideS ? edata_s : edata_d;

    int kv[EPT], ov[EPT];
    {
        const int4* k4 = (const int4*)(keyp + my0);
        const int4* o4 = (const int4*)(othp + my0);
        if (my0 + EPT <= e1) {
            int4 a = k4[0], b = k4[1];
            kv[0] = a.x; kv[1] = a.y; kv[2] = a.z; kv[3] = a.w;
            kv[4] = b.x; kv[5] = b.y; kv[6] = b.z; kv[7] = b.w;
            int4 c = o4[0], d = o4[1];
            ov[0] = c.x; ov[1] = c.y; ov[2] = c.z; ov[3] = c.w;
            ov[4] = d.x; ov[5] = d.y; ov[6] = d.z; ov[7] = d.w;
        } else {
#pragma unroll
            for (int k = 0; k < EPT; ++k) {
                int i = my0 + k;
                kv[k] = (i < e1) ? keyp[i] : 0;
                ov[k] = (i < e1) ? othp[i] : 0;
            }
        }
    }
    int gvv[EPT];
    if (sideS) {
#pragma unroll
        for (int k = 0; k < EPT; ++k)
            gvv[k] = (my0 + k < e1) ? batch[ov[k]] : 0;
    }

    int pay[EPT];
    unsigned short pb[EPT], pr[EPT];

    for (int i = t; i < NBUK; i += 512) lofs[i] = 0;
    __syncthreads();
#pragma unroll
    for (int k = 0; k < EPT; ++k) {
        int i = my0 + k;
        if (i < e1) {
            int b = kv[k] >> 7;
            int r = atomicAdd(&lofs[b], 1);
            pay[k] = sideS ? (((kv[k] & 127) << 23) | (gvv[k] << 17) | ov[k])
                           : (((kv[k] & 127) << 17) | ov[k]);
            pb[k] = (unsigned short)b;
            pr[k] = (unsigned short)r;
        }
    }
    __syncthreads();
    // pair-per-thread exclusive scan of lofs[NBUK] (512 threads, 8 waves)
    {
        int lane = t & 63;
        int w = t >> 6;
        int b0i = 2 * t, b1i = 2 * t + 1;
        int c0 = (b0i < NBUK) ? lofs[b0i] : 0;
        int c1 = (b1i < NBUK) ? lofs[b1i] : 0;
        int v = c0 + c1;
        int s = v;
#pragma unroll
        for (int off = 1; off < 64; off <<= 1) {
            int u = __shfl_up(s, off, 64);
            if (lane >= off) s += u;
        }
        if (lane == 63) stmp[w] = s;
        __syncthreads();
        if (t < 8) {
            int ws2 = stmp[t];
#pragma unroll
            for (int off = 1; off < 8; off <<= 1) {
                int u = __shfl_up(ws2, off, 8);
                if (t >= off) ws2 += u;
            }
            stmp[t] = ws2;
        }
        __syncthreads();
        int basew = (w > 0) ? stmp[w - 1] : 0;
        int ex = basew + (s - v);
        if (b0i < NBUK) {
            lofs[b0i] = ex;
            gbase[b0i] = b0i * CAPE + (c0 ? atomicAdd(&cur[b0i], c0) : 0);
        }
        if (b1i < NBUK) {
            lofs[b1i] = ex + c0;
            gbase[b1i] = b1i * CAPE + (c1 ? atomicAdd(&cur[b1i], c1) : 0);
        }
    }
    __syncthreads();
#pragma unroll
    for (int k = 0; k < EPT; ++k) {
        int i = my0 + k;
        if (i < e1) {
            int pos = lofs[pb[k]] + pr[k];
            stage[pos] = pay[k];
            bkt[pos] = pb[k];
        }
    }
    __syncthreads();
#pragma unroll
    for (int k = 0; k < EPT; ++k) {
        int j = k * 512 + t;
        if (j < ne) {
            int b = bkt[j];
            edata[gbase[b] + (j - lofs[b])] = stage[j];
        }
    }
}

// ---------------- indeg + per-chunk sort: dis/xd + ed2 (sorted, coalesced) + gofs ----------------

__global__ __launch_bounds__(512) void k_indeg(const int* __restrict__ edata_d,
                                               const int* __restrict__ cur_d,
                                               const float* __restrict__ x,
                                               float* __restrict__ dis,
                                               float4* __restrict__ xd,
                                               int* __restrict__ ed2,
                                               int* __restrict__ gofs) {
    __shared__ int cnt[CHUNK];
    __shared__ int ofs[CHUNK];
    __shared__ int wtot[1];
    __shared__ int stage[CAPE];
    int t = threadIdx.x;
    int lane = t & 63;
    int b = blockIdx.x;
    if (t < CHUNK) cnt[t] = 0;
    __syncthreads();
    int n_e = cur_d[b];
    int pv[6], rv[6];
#pragma unroll
    for (int k = 0; k < 6; ++k) {
        int i = t + k * 512;
        pv[k] = (i < n_e) ? edata_d[(size_t)b * CAPE + i] : -1;
    }
#pragma unroll
    for (int k = 0; k < 6; ++k)
        if (pv[k] != -1) rv[k] = atomicAdd(&cnt[pv[k] >> 17], 1);
    __syncthreads();
    {
        int v = (t < CHUNK) ? cnt[t] : 0;
        int s = v;
#pragma unroll
        for (int off = 1; off < 64; off <<= 1) {
            int u = __shfl_up(s, off, 64);
            if (lane >= off) s += u;
        }
        if (t == 63) wtot[0] = s;
        __syncthreads();
        if (t < CHUNK) {
            int o = s - v + ((t >= 64) ? wtot[0] : 0);
            ofs[t] = o;
            gofs[b * CHUNK + t] = o;
            int node = b * CHUNK + t;
            if (node < N_NODES) {
                float d = rsqrtf((float)(cnt[t] + 1));
                dis[node] = d;
                float4 p;
                p.x = x[node * 3 + 0] * d;
                p.y = x[node * 3 + 1] * d;
                p.z = x[node * 3 + 2] * d;
                p.w = d;
                xd[node] = p;
            }
        }
    }
    __syncthreads();
#pragma unroll
    for (int k = 0; k < 6; ++k)
        if (pv[k] != -1) stage[ofs[pv[k] >> 17] + rv[k]] = pv[k];
    __syncthreads();
    for (int j = t; j < n_e; j += 512)
        ed2[(size_t)b * CAPE + j] = stage[j];
}

// ---------------- aggregation + coefficients + MFMA (persistent) ----------------

__global__ __launch_bounds__(512) void k_aggz(const int* __restrict__ ed2,
                                              const int* __restrict__ edata_s,
                                              const int* __restrict__ cur_d,
                                              const int* __restrict__ cur_s,
                                              const int* __restrict__ gofs,
                                              const int* __restrict__ batch,
                                              const float* __restrict__ dis,
                                              const float4* __restrict__ xd,
                                              const float* __restrict__ W1,
                                              const float* __restrict__ b1,
                                              float* __restrict__ zpart) {
    __shared__ __align__(16) char smem[(DIM + NG) * UP * 2];   // 52224 B
    __shared__ uint2 agb[CHUNK];
    __shared__ float disl[CHUNK];
    float* ctile = (float*)smem;
    unsigned short* uT = (unsigned short*)smem;
    int* ofs = (int*)(smem + 33792);   // gap; dead after P1, overwritten by uT
    unsigned short* cbf = (unsigned short*)(smem + DIM * UP * 2);

    int t = threadIdx.x;
    int lane = t & 63;
    int wave = t >> 6;
    int q = lane >> 4, l15 = lane & 15;

    for (int c = blockIdx.x; c < NBUK; c += GRID_A) {
        int base = c * CHUNK;
        int n_d = cur_d[c];
        int n_s = cur_s[c];

        int ps[6];
        float dd[6];
#pragma unroll
        for (int k = 0; k < 6; ++k) {
            int i = t + k * 512;
            ps[k] = (i < n_s) ? edata_s[(size_t)c * CAPE + i] : -1;
        }
#pragma unroll
        for (int k = 0; k < 6; ++k)
            if (ps[k] != -1) dd[k] = dis[ps[k] & 0x1FFFF];

        {
            float4 z4 = {0.f, 0.f, 0.f, 0.f};
            float4* c4 = (float4*)smem;
            for (int i = t; i < 2112; i += 512) c4[i] = z4;
        }
        if (t < CHUNK) {
            ofs[t] = gofs[c * CHUNK + t];
            int node = base + t;
            disl[t] = (node < N_NODES) ? dis[node] : 0.f;
        }
        __syncthreads();

        {
#pragma unroll
            for (int k = 0; k < 6; ++k)
                if (ps[k] != -1) {
                    int sl = ps[k] >> 23;
                    atomicAdd(&ctile[((ps[k] >> 17) & 63) * ZP + sl], disl[sl] * dd[k]);
                }
            if (t < CHUNK) {
                int node = base + t;
                if (node < N_NODES) {
                    float w = disl[t];
                    atomicAdd(&ctile[batch[node] * ZP + t], w * w);
                }
            }
            int d = t >> 2, qq = t & 3;
            int o = ofs[d];
            int e = (d == CHUNK - 1) ? n_d : ofs[d + 1];
            const int* run = ed2 + (size_t)c * CAPE;
            float sx = 0.f, sy = 0.f, sz = 0.f;
            int j = o + qq;
            for (; j + 4 < e; j += 8) {
                int p0 = run[j], p1 = run[j + 4];
                float4 y0 = xd[p0 & 0x1FFFF];
                float4 y1 = xd[p1 & 0x1FFFF];
                sx += y0.x + y1.x;
                sy += y0.y + y1.y;
                sz += y0.z + y1.z;
            }
            for (; j < e; j += 4) {
                int p = run[j];
                float4 y = xd[p & 0x1FFFF];
                sx += y.x; sy += y.y; sz += y.z;
            }
            sx += __shfl_xor(sx, 1, 64); sx += __shfl_xor(sx, 2, 64);
            sy += __shfl_xor(sy, 1, 64); sy += __shfl_xor(sy, 2, 64);
            sz += __shfl_xor(sz, 1, 64); sz += __shfl_xor(sz, 2, 64);
            if (qq == 0) {
                int node = base + d;
                uint2 p;
                if (node < N_NODES) {
                    float4 self = xd[node];
                    float ddd = self.w;
                    float ox = (sx + self.x) * ddd;
                    float oy = (sy + self.y) * ddd;
                    float oz = (sz + self.z) * ddd;
                    p.x = (unsigned int)f2bf(ox) | ((unsigned int)f2bf(oy) << 16);
                    p.y = (unsigned int)f2bf(oz) | ((unsigned int)f2bf(ddd) << 16);
                } else {
                    p.x = 0u; p.y = 0u;
                }
                agb[d] = p;
            }
        }
        __syncthreads();

        {
            int g = t >> 3, s0 = (t & 7) * 16;
            const float* cr = &ctile[g * ZP + s0];
            float4 f0 = *(const float4*)cr;
            float4 f1 = *(const float4*)(cr + 4);
            float4 f2 = *(const float4*)(cr + 8);
            float4 f3 = *(const float4*)(cr + 12);
            uint4 o0, o1;
            o0.x = (unsigned int)f2bf(f0.x) | ((unsigned int)f2bf(f0.y) << 16);
            o0.y = (unsigned int)f2bf(f0.z) | ((unsigned int)f2bf(f0.w) << 16);
            o0.z = (unsigned int)f2bf(f1.x) | ((unsigned int)f2bf(f1.y) << 16);
            o0.w = (unsigned int)f2bf(f1.z) | ((unsigned int)f2bf(f1.w) << 16);
            o1.x = (unsigned int)f2bf(f2.x) | ((unsigned int)f2bf(f2.y) << 16);
            o1.y = (unsigned int)f2bf(f2.z) | ((unsigned int)f2bf(f2.w) << 16);
            o1.z = (unsigned int)f2bf(f3.x) | ((unsigned int)f2bf(f3.y) << 16);
            o1.w = (unsigned int)f2bf(f3.z) | ((unsigned int)f2bf(f3.w) << 16);
            *(uint4*)&cbf[g * UP + s0] = o0;
            *(uint4*)&cbf[g * UP + s0 + 8] = o1;
        }
        __syncthreads();

        {
            int n = t >> 2;
            int sh = (t & 3) * 32;
            float w0 = W1[n], w1 = W1[DIM + n], w2 = W1[2 * DIM + n], bb = b1[n];
            for (int sp = 0; sp < 32; sp += 2) {
                uint2 pa = agb[sh + sp];
                uint2 pbv = agb[sh + sp + 1];
                float u0 = fmaxf(fmaf(bflo(pa.x), w0, fmaf(bfhi(pa.x), w1, fmaf(bflo(pa.y), w2, bb))), 0.f);
                float u1 = fmaxf(fmaf(bflo(pbv.x), w0, fmaf(bfhi(pbv.x), w1, fmaf(bflo(pbv.y), w2, bb))), 0.f);
                unsigned int pk = (unsigned int)f2bf(u0) | ((unsigned int)f2bf(u1) << 16);
                *(unsigned int*)&uT[n * UP + sh + sp] = pk;
            }
        }
        __syncthreads();

        {
            f32x4 acc[4];
#pragma unroll
            for (int nt = 0; nt < 4; ++nt) acc[nt] = (f32x4){0.f, 0.f, 0.f, 0.f};
#pragma unroll
            for (int ks = 0; ks < 4; ++ks) {
                int s0 = ks * 32 + q * 8;
                union { uint4 r; bf16x8 v; } A, B;
                A.r = *(const uint4*)&uT[(wave * 16 + l15) * UP + s0];
#pragma unroll
                for (int nt = 0; nt < 4; ++nt) {
                    B.r = *(const uint4*)&cbf[(nt * 16 + l15) * UP + s0];
                    acc[nt] = __builtin_amdgcn_mfma_f32_16x16x32_bf16(A.v, B.v, acc[nt], 0, 0, 0);
                }
            }
            float* zp = zpart + (size_t)c * (NG * DIM);
#pragma unroll
            for (int nt = 0; nt < 4; ++nt) {
                int g = nt * 16 + l15;
                float4 o;
                o.x = acc[nt][0]; o.y = acc[nt][1]; o.z = acc[nt][2]; o.w = acc[nt][3];
                *(float4*)&zp[g * DIM + wave * 16 + q * 4] = o;
            }
        }
        __syncthreads();
    }
}

// ---------------- zpart reduction (float4, 32 partials) ----------------

__global__ __launch_bounds__(256) void k_zred1(const float* __restrict__ zpart,
                                               float* __restrict__ zpart2) {
    int id = blockIdx.x * 256 + threadIdx.x;      // [0, NPART*2048)
    int i4 = id & (2048 - 1);
    int p = id >> 11;
    int b0 = p * ZRB;
    int b1 = min(b0 + ZRB, NBUK);
    const float4* base = (const float4*)zpart + i4;
    float4 s0 = {0.f, 0.f, 0.f, 0.f}, s1 = {0.f, 0.f, 0.f, 0.f};
    int b = b0;
    for (; b + 1 < b1; b += 2) {
        float4 a = base[(size_t)(b + 0) * 2048];
        float4 c = base[(size_t)(b + 1) * 2048];
        s0.x += a.x; s0.y += a.y; s0.z += a.z; s0.w += a.w;
        s1.x += c.x; s1.y += c.y; s1.z += c.z; s1.w += c.w;
    }
    for (; b < b1; ++b) {
        float4 a = base[(size_t)b * 2048];
        s0.x += a.x; s0.y += a.y; s0.z += a.z; s0.w += a.w;
    }
    float4 o;
    o.x = s0.x + s1.x; o.y = s0.y + s1.y; o.z = s0.z + s1.z; o.w = s0.w + s1.w;
    ((float4*)zpart2)[(size_t)p * 2048 + i4] = o;
}

// ---------------- fused head: partial-sum + W2 mix + Wf GEMV (256 blocks) ----------------
// Block = (g, action-quarter). W2 GEMV is recomputed per quarter (4M FMA total, free);
// saves one dispatch + gap vs split poolmix/final.

__global__ __launch_bounds__(128) void k_poolfinal2(const float* __restrict__ zpart2,
                                                    const float* __restrict__ W2,
                                                    const float* __restrict__ b2,
                                                    const int* __restrict__ batch,
                                                    const float* __restrict__ Wf,
                                                    const float* __restrict__ bfv,
                                                    float* __restrict__ out) {
    __shared__ float zr[DIM];
    __shared__ float emb[DIM];
    __shared__ int se[2];
    int g = blockIdx.x >> 2;
    int quarter = blockIdx.x & 3;
    int t = threadIdx.x;
    if (t < 2) {
        int target = g + t;
        int lo = 0, hi = N_NODES;
        while (lo < hi) {
            int mid = (lo + hi) >> 1;
            if (batch[mid] < target) lo = mid + 1; else hi = mid;
        }
        se[t] = lo;
    }
    {
        const float* base = zpart2 + g * DIM + t;
        float acc = 0.f;
#pragma unroll
        for (int p = 0; p < NPART; ++p) acc += base[(size_t)p * (NG * DIM)];
        zr[t] = acc;
    }
    __syncthreads();
    float inv = 1.0f / fmaxf((float)(se[1] - se[0]), 1.0f);
    float acc = 0.f;
#pragma unroll 4
    for (int k = 0; k < DIM; ++k) acc = fmaf(zr[k], W2[k * DIM + t], acc);
    emb[t] = acc * inv + b2[t];
    __syncthreads();
    int a = quarter * 128 + t;
    float s0 = 0.f, s1 = 0.f, s2 = 0.f, s3 = 0.f;
#pragma unroll
    for (int c = 0; c < DIM; c += 4) {
        s0 = fmaf(emb[c + 0], Wf[(c + 0) * ACT + a], s0);
        s1 = fmaf(emb[c + 1], Wf[(c + 1) * ACT + a], s1);
        s2 = fmaf(emb[c + 2], Wf[(c + 2) * ACT + a], s2);
        s3 = fmaf(emb[c + 3], Wf[(c + 3) * ACT + a], s3);
    }
    out[g * ACT + a] = (s0 + s1) + (s2 + s3) + bfv[a];
}

// ---------------- launch ----------------

static inline size_t align256(size_t x) { return (x + 255) & ~(size_t)255; }

extern "C" void kernel_launch(void* const* d_in, const int* in_sizes, int n_in,
                              void* d_out, int out_size, void* d_ws, size_t ws_size,
                              hipStream_t stream) {
    const float* x  = (const float*)d_in[0];
    const int*   ei = (const int*)d_in[1];
    const int*   batch = (const int*)d_in[2];
    const float* W1 = (const float*)d_in[3];
    const float* b1 = (const float*)d_in[4];
    const float* W2 = (const float*)d_in[5];
    const float* b2 = (const float*)d_in[6];
    const float* Wf = (const float*)d_in[7];
    const float* bf = (const float*)d_in[8];
    float* out = (float*)d_out;

    const int* src = ei;
    const int* dst = ei + N_EDGES;

    char* ws = (char*)d_ws;
    size_t off = 0;
    int*   cur     = (int*)(ws + off);   off = align256(off + (size_t)NBUK2 * 4);
    int*   edata_d = (int*)(ws + off);   off = align256(off + (size_t)NBUK * CAPE * 4);
    int*   edata_s = (int*)(ws + off);   off = align256(off + (size_t)NBUK * CAPE * 4);
    int*   ed2     = (int*)(ws + off);   off = align256(off + (size_t)NBUK * CAPE * 4);
    int*   gofs    = (int*)(ws + off);   off = align256(off + (size_t)NBUK * CHUNK * 4);
    float* dis     = (float*)(ws + off); off = align256(off + N_NODES * 4);
    float4* xd     = (float4*)(ws + off); off = align256(off + (size_t)N_NODES * 16);
    float* zpart   = (float*)(ws + off); off = align256(off + (size_t)NBUK * NG * DIM * 4);
    float* zpart2  = (float*)(ws + off); off = align256(off + (size_t)NPART * NG * DIM * 4);

    k_zero<<<2, 1024, 0, stream>>>(cur);
    k_bfill<<<2 * NBLK_E, 512, 0, stream>>>(src, dst, batch, cur, cur + NBUK, edata_d, edata_s);
    k_indeg<<<NBUK, 512, 0, stream>>>(edata_d, cur, x, dis, xd, ed2, gofs);
    k_aggz<<<GRID_A, 512, 0, stream>>>(ed2, edata_s, cur, cur + NBUK, gofs, batch, dis, xd, W1, b1, zpart);
    k_zred1<<<NPART * NG * DIM / 1024, 256, 0, stream>>>(zpart, zpart2);
    k_poolfinal2<<<NG * 4, 128, 0, stream>>>(zpart2, W2, b2, batch, Wf, bf, out);
}

// Round 14
// 166.579 us; speedup vs baseline: 1.1383x; 1.1383x over previous
//
#include <hip/hip_runtime.h>

#define N_NODES 100000
#define N_EDGES 1600000
#define DIM 128
#define ACT 512
#define NG 64
#define CHUNK 128
#define NBUK 782            // ceil(N_NODES/CHUNK)
#define NBUK2 (2 * NBUK)
#define EB 8192             // edges per partition block (R12-verified best)
#define NBLK_E 196          // ceil(N_EDGES/EB)
#define EPT 8               // edges per thread in bfill (EB/1024)
#define UP 136              // bf16 row pitch for uT/cbf (16B-aligned rows)
#define ZP 132              // fp32 ctile pitch (bank-spread, b128-aligned)
#define NPART 32            // zred partial reducers per output
#define CAPE 2688           // per-bucket edata capacity (mean 2048, sd ~45 -> 14 sigma)
#define ZRB 25              // buckets per zred1 partial (32*25 >= 782)
#define GRID_A 768          // aggz persistent grid: 3 blocks/CU x 256 CU

typedef __attribute__((ext_vector_type(8))) short bf16x8;
typedef __attribute__((ext_vector_type(4))) float f32x4;

__device__ __forceinline__ unsigned short f2bf(float f) {
    union { float f; unsigned int i; } v;
    v.f = f;
    unsigned int i = v.i;
    i += 0x7fffu + ((i >> 16) & 1u);   // RNE
    return (unsigned short)(i >> 16);
}
__device__ __forceinline__ float bflo(unsigned int u) {
    union { unsigned int i; float f; } v;
    v.i = u << 16;
    return v.f;
}
__device__ __forceinline__ float bfhi(unsigned int u) {
    union { unsigned int i; float f; } v;
    v.i = u & 0xffff0000u;
    return v.f;
}

// ---------------- cursor zero ----------------

__global__ __launch_bounds__(1024) void k_zero(int* __restrict__ cur) {
    int i = blockIdx.x * 1024 + threadIdx.x;
    if (i < NBUK2) cur[i] = 0;
}

// ---------------- bucket partition via atomic segment claiming ----------------
// Side-split: blocks [0,NBLK_E) sort side D, [NBLK_E,2*NBLK_E) sort side S.
// EB=8192 x 1024 threads (R12 config — R13's EB=4096 split regressed: doubled
// cursor atomics + fragmented sub-cacheline scatter segments).
__global__ __launch_bounds__(1024) void k_bfill(const int* __restrict__ src,
                                                const int* __restrict__ dst,
                                                const int* __restrict__ batch,
                                                int* __restrict__ cur_d,
                                                int* __restrict__ cur_s,
                                                int* __restrict__ edata_d,
                                                int* __restrict__ edata_s) {
    __shared__ int gbase[NBUK];
    __shared__ int lofs[NBUK];
    __shared__ int stage[EB];
    __shared__ unsigned short bkt[EB];
    __shared__ int stmp[16];
    int t = threadIdx.x;
    int blk = blockIdx.x;
    int sideS = (blk >= NBLK_E) ? 1 : 0;
    int pblk = sideS ? blk - NBLK_E : blk;
    int e0 = pblk * EB;
    int e1 = min(e0 + EB, N_EDGES);
    int ne = e1 - e0;
    int my0 = e0 + t * EPT;

    const int* keyp = sideS ? src : dst;
    const int* othp = sideS ? dst : src;
    int* cur = sideS ? cur_s : cur_d;
    int* edata = sideS ? edata_s : edata_d;

    int kv[EPT], ov[EPT];
    {
        const int4* k4 = (const int4*)(keyp + my0);
        const int4* o4 = (const int4*)(othp + my0);
        if (my0 + EPT <= e1) {
            int4 a = k4[0], b = k4[1];
            kv[0] = a.x; kv[1] = a.y; kv[2] = a.z; kv[3] = a.w;
            kv[4] = b.x; kv[5] = b.y; kv[6] = b.z; kv[7] = b.w;
            int4 c = o4[0], d = o4[1];
            ov[0] = c.x; ov[1] = c.y; ov[2] = c.z; ov[3] = c.w;
            ov[4] = d.x; ov[5] = d.y; ov[6] = d.z; ov[7] = d.w;
        } else {
#pragma unroll
            for (int k = 0; k < EPT; ++k) {
                int i = my0 + k;
                kv[k] = (i < e1) ? keyp[i] : 0;
                ov[k] = (i < e1) ? othp[i] : 0;
            }
        }
    }
    int gvv[EPT];
    if (sideS) {
#pragma unroll
        for (int k = 0; k < EPT; ++k)
            gvv[k] = (my0 + k < e1) ? batch[ov[k]] : 0;
    }

    int pay[EPT];
    unsigned short pb[EPT], pr[EPT];

    for (int i = t; i < NBUK; i += 1024) lofs[i] = 0;
    __syncthreads();
#pragma unroll
    for (int k = 0; k < EPT; ++k) {
        int i = my0 + k;
        if (i < e1) {
            int b = kv[k] >> 7;
            int r = atomicAdd(&lofs[b], 1);
            pay[k] = sideS ? (((kv[k] & 127) << 23) | (gvv[k] << 17) | ov[k])
                           : (((kv[k] & 127) << 17) | ov[k]);
            pb[k] = (unsigned short)b;
            pr[k] = (unsigned short)r;
        }
    }
    __syncthreads();
    {
        int lane = t & 63;
        int w = t >> 6;
        int c = (t < NBUK) ? lofs[t] : 0;
        int s = c;
#pragma unroll
        for (int off = 1; off < 64; off <<= 1) {
            int u = __shfl_up(s, off, 64);
            if (lane >= off) s += u;
        }
        if (lane == 63) stmp[w] = s;
        __syncthreads();
        if (t < 16) {
            int ws = stmp[t];
#pragma unroll
            for (int off = 1; off < 16; off <<= 1) {
                int u = __shfl_up(ws, off, 64);
                if (t >= off) ws += u;
            }
            stmp[t] = ws;
        }
        __syncthreads();
        int basew = (w > 0) ? stmp[w - 1] : 0;
        int ex = basew + (s - c);
        if (t < NBUK) {
            lofs[t] = ex;
            gbase[t] = t * CAPE + (c ? atomicAdd(&cur[t], c) : 0);
        }
    }
    __syncthreads();
#pragma unroll
    for (int k = 0; k < EPT; ++k) {
        int i = my0 + k;
        if (i < e1) {
            int pos = lofs[pb[k]] + pr[k];
            stage[pos] = pay[k];
            bkt[pos] = pb[k];
        }
    }
    __syncthreads();
#pragma unroll
    for (int k = 0; k < EPT; ++k) {
        int j = k * 1024 + t;
        if (j < ne) {
            int b = bkt[j];
            edata[gbase[b] + (j - lofs[b])] = stage[j];
        }
    }
}

// ---------------- indeg + per-chunk sort: dis/xd + ed2 (sorted, coalesced) + gofs ----------------

__global__ __launch_bounds__(512) void k_indeg(const int* __restrict__ edata_d,
                                               const int* __restrict__ cur_d,
                                               const float* __restrict__ x,
                                               float* __restrict__ dis,
                                               float4* __restrict__ xd,
                                               int* __restrict__ ed2,
                                               int* __restrict__ gofs) {
    __shared__ int cnt[CHUNK];
    __shared__ int ofs[CHUNK];
    __shared__ int wtot[1];
    __shared__ int stage[CAPE];
    int t = threadIdx.x;
    int lane = t & 63;
    int b = blockIdx.x;
    if (t < CHUNK) cnt[t] = 0;
    __syncthreads();
    int n_e = cur_d[b];
    int pv[6], rv[6];
#pragma unroll
    for (int k = 0; k < 6; ++k) {
        int i = t + k * 512;
        pv[k] = (i < n_e) ? edata_d[(size_t)b * CAPE + i] : -1;
    }
#pragma unroll
    for (int k = 0; k < 6; ++k)
        if (pv[k] != -1) rv[k] = atomicAdd(&cnt[pv[k] >> 17], 1);
    __syncthreads();
    {
        int v = (t < CHUNK) ? cnt[t] : 0;
        int s = v;
#pragma unroll
        for (int off = 1; off < 64; off <<= 1) {
            int u = __shfl_up(s, off, 64);
            if (lane >= off) s += u;
        }
        if (t == 63) wtot[0] = s;
        __syncthreads();
        if (t < CHUNK) {
            int o = s - v + ((t >= 64) ? wtot[0] : 0);
            ofs[t] = o;
            gofs[b * CHUNK + t] = o;
            int node = b * CHUNK + t;
            if (node < N_NODES) {
                float d = rsqrtf((float)(cnt[t] + 1));
                dis[node] = d;
                float4 p;
                p.x = x[node * 3 + 0] * d;
                p.y = x[node * 3 + 1] * d;
                p.z = x[node * 3 + 2] * d;
                p.w = d;
                xd[node] = p;
            }
        }
    }
    __syncthreads();
#pragma unroll
    for (int k = 0; k < 6; ++k)
        if (pv[k] != -1) stage[ofs[pv[k] >> 17] + rv[k]] = pv[k];
    __syncthreads();
    for (int j = t; j < n_e; j += 512)
        ed2[(size_t)b * CAPE + j] = stage[j];
}

// ---------------- aggregation + coefficients + MFMA (persistent) ----------------

__global__ __launch_bounds__(512) void k_aggz(const int* __restrict__ ed2,
                                              const int* __restrict__ edata_s,
                                              const int* __restrict__ cur_d,
                                              const int* __restrict__ cur_s,
                                              const int* __restrict__ gofs,
                                              const int* __restrict__ batch,
                                              const float* __restrict__ dis,
                                              const float4* __restrict__ xd,
                                              const float* __restrict__ W1,
                                              const float* __restrict__ b1,
                                              float* __restrict__ zpart) {
    __shared__ __align__(16) char smem[(DIM + NG) * UP * 2];   // 52224 B
    __shared__ uint2 agb[CHUNK];
    __shared__ float disl[CHUNK];
    float* ctile = (float*)smem;
    unsigned short* uT = (unsigned short*)smem;
    int* ofs = (int*)(smem + 33792);   // gap; dead after P1, overwritten by uT
    unsigned short* cbf = (unsigned short*)(smem + DIM * UP * 2);

    int t = threadIdx.x;
    int lane = t & 63;
    int wave = t >> 6;
    int q = lane >> 4, l15 = lane & 15;

    for (int c = blockIdx.x; c < NBUK; c += GRID_A) {
        int base = c * CHUNK;
        int n_d = cur_d[c];
        int n_s = cur_s[c];

        int ps[6];
        float dd[6];
#pragma unroll
        for (int k = 0; k < 6; ++k) {
            int i = t + k * 512;
            ps[k] = (i < n_s) ? edata_s[(size_t)c * CAPE + i] : -1;
        }
#pragma unroll
        for (int k = 0; k < 6; ++k)
            if (ps[k] != -1) dd[k] = dis[ps[k] & 0x1FFFF];

        {
            float4 z4 = {0.f, 0.f, 0.f, 0.f};
            float4* c4 = (float4*)smem;
            for (int i = t; i < 2112; i += 512) c4[i] = z4;
        }
        if (t < CHUNK) {
            ofs[t] = gofs[c * CHUNK + t];
            int node = base + t;
            disl[t] = (node < N_NODES) ? dis[node] : 0.f;
        }
        __syncthreads();

        {
#pragma unroll
            for (int k = 0; k < 6; ++k)
                if (ps[k] != -1) {
                    int sl = ps[k] >> 23;
                    atomicAdd(&ctile[((ps[k] >> 17) & 63) * ZP + sl], disl[sl] * dd[k]);
                }
            if (t < CHUNK) {
                int node = base + t;
                if (node < N_NODES) {
                    float w = disl[t];
                    atomicAdd(&ctile[batch[node] * ZP + t], w * w);
                }
            }
            int d = t >> 2, qq = t & 3;
            int o = ofs[d];
            int e = (d == CHUNK - 1) ? n_d : ofs[d + 1];
            const int* run = ed2 + (size_t)c * CAPE;
            float sx = 0.f, sy = 0.f, sz = 0.f;
            int j = o + qq;
            for (; j + 4 < e; j += 8) {
                int p0 = run[j], p1 = run[j + 4];
                float4 y0 = xd[p0 & 0x1FFFF];
                float4 y1 = xd[p1 & 0x1FFFF];
                sx += y0.x + y1.x;
                sy += y0.y + y1.y;
                sz += y0.z + y1.z;
            }
            for (; j < e; j += 4) {
                int p = run[j];
                float4 y = xd[p & 0x1FFFF];
                sx += y.x; sy += y.y; sz += y.z;
            }
            sx += __shfl_xor(sx, 1, 64); sx += __shfl_xor(sx, 2, 64);
            sy += __shfl_xor(sy, 1, 64); sy += __shfl_xor(sy, 2, 64);
            sz += __shfl_xor(sz, 1, 64); sz += __shfl_xor(sz, 2, 64);
            if (qq == 0) {
                int node = base + d;
                uint2 p;
                if (node < N_NODES) {
                    float4 self = xd[node];
                    float ddd = self.w;
                    float ox = (sx + self.x) * ddd;
                    float oy = (sy + self.y) * ddd;
                    float oz = (sz + self.z) * ddd;
                    p.x = (unsigned int)f2bf(ox) | ((unsigned int)f2bf(oy) << 16);
                    p.y = (unsigned int)f2bf(oz) | ((unsigned int)f2bf(ddd) << 16);
                } else {
                    p.x = 0u; p.y = 0u;
                }
                agb[d] = p;
            }
        }
        __syncthreads();

        {
            int g = t >> 3, s0 = (t & 7) * 16;
            const float* cr = &ctile[g * ZP + s0];
            float4 f0 = *(const float4*)cr;
            float4 f1 = *(const float4*)(cr + 4);
            float4 f2 = *(const float4*)(cr + 8);
            float4 f3 = *(const float4*)(cr + 12);
            uint4 o0, o1;
            o0.x = (unsigned int)f2bf(f0.x) | ((unsigned int)f2bf(f0.y) << 16);
            o0.y = (unsigned int)f2bf(f0.z) | ((unsigned int)f2bf(f0.w) << 16);
            o0.z = (unsigned int)f2bf(f1.x) | ((unsigned int)f2bf(f1.y) << 16);
            o0.w = (unsigned int)f2bf(f1.z) | ((unsigned int)f2bf(f1.w) << 16);
            o1.x = (unsigned int)f2bf(f2.x) | ((unsigned int)f2bf(f2.y) << 16);
            o1.y = (unsigned int)f2bf(f2.z) | ((unsigned int)f2bf(f2.w) << 16);
            o1.z = (unsigned int)f2bf(f3.x) | ((unsigned int)f2bf(f3.y) << 16);
            o1.w = (unsigned int)f2bf(f3.z) | ((unsigned int)f2bf(f3.w) << 16);
            *(uint4*)&cbf[g * UP + s0] = o0;
            *(uint4*)&cbf[g * UP + s0 + 8] = o1;
        }
        __syncthreads();

        {
            int n = t >> 2;
            int sh = (t & 3) * 32;
            float w0 = W1[n], w1 = W1[DIM + n], w2 = W1[2 * DIM + n], bb = b1[n];
            for (int sp = 0; sp < 32; sp += 2) {
                uint2 pa = agb[sh + sp];
                uint2 pbv = agb[sh + sp + 1];
                float u0 = fmaxf(fmaf(bflo(pa.x), w0, fmaf(bfhi(pa.x), w1, fmaf(bflo(pa.y), w2, bb))), 0.f);
                float u1 = fmaxf(fmaf(bflo(pbv.x), w0, fmaf(bfhi(pbv.x), w1, fmaf(bflo(pbv.y), w2, bb))), 0.f);
                unsigned int pk = (unsigned int)f2bf(u0) | ((unsigned int)f2bf(u1) << 16);
                *(unsigned int*)&uT[n * UP + sh + sp] = pk;
            }
        }
        __syncthreads();

        {
            f32x4 acc[4];
#pragma unroll
            for (int nt = 0; nt < 4; ++nt) acc[nt] = (f32x4){0.f, 0.f, 0.f, 0.f};
#pragma unroll
            for (int ks = 0; ks < 4; ++ks) {
                int s0 = ks * 32 + q * 8;
                union { uint4 r; bf16x8 v; } A, B;
                A.r = *(const uint4*)&uT[(wave * 16 + l15) * UP + s0];
#pragma unroll
                for (int nt = 0; nt < 4; ++nt) {
                    B.r = *(const uint4*)&cbf[(nt * 16 + l15) * UP + s0];
                    acc[nt] = __builtin_amdgcn_mfma_f32_16x16x32_bf16(A.v, B.v, acc[nt], 0, 0, 0);
                }
            }
            float* zp = zpart + (size_t)c * (NG * DIM);
#pragma unroll
            for (int nt = 0; nt < 4; ++nt) {
                int g = nt * 16 + l15;
                float4 o;
                o.x = acc[nt][0]; o.y = acc[nt][1]; o.z = acc[nt][2]; o.w = acc[nt][3];
                *(float4*)&zp[g * DIM + wave * 16 + q * 4] = o;
            }
        }
        __syncthreads();
    }
}

// ---------------- zpart reduction (float4, 32 partials) ----------------

__global__ __launch_bounds__(256) void k_zred1(const float* __restrict__ zpart,
                                               float* __restrict__ zpart2) {
    int id = blockIdx.x * 256 + threadIdx.x;      // [0, NPART*2048)
    int i4 = id & (2048 - 1);
    int p = id >> 11;
    int b0 = p * ZRB;
    int b1 = min(b0 + ZRB, NBUK);
    const float4* base = (const float4*)zpart + i4;
    float4 s0 = {0.f, 0.f, 0.f, 0.f}, s1 = {0.f, 0.f, 0.f, 0.f};
    int b = b0;
    for (; b + 1 < b1; b += 2) {
        float4 a = base[(size_t)(b + 0) * 2048];
        float4 c = base[(size_t)(b + 1) * 2048];
        s0.x += a.x; s0.y += a.y; s0.z += a.z; s0.w += a.w;
        s1.x += c.x; s1.y += c.y; s1.z += c.z; s1.w += c.w;
    }
    for (; b < b1; ++b) {
        float4 a = base[(size_t)b * 2048];
        s0.x += a.x; s0.y += a.y; s0.z += a.z; s0.w += a.w;
    }
    float4 o;
    o.x = s0.x + s1.x; o.y = s0.y + s1.y; o.z = s0.z + s1.z; o.w = s0.w + s1.w;
    ((float4*)zpart2)[(size_t)p * 2048 + i4] = o;
}

// ---------------- fused head: partial-sum + W2 mix + Wf GEMV (256 blocks) ----------------

__global__ __launch_bounds__(128) void k_poolfinal2(const float* __restrict__ zpart2,
                                                    const float* __restrict__ W2,
                                                    const float* __restrict__ b2,
                                                    const int* __restrict__ batch,
                                                    const float* __restrict__ Wf,
                                                    const float* __restrict__ bfv,
                                                    float* __restrict__ out) {
    __shared__ float zr[DIM];
    __shared__ float emb[DIM];
    __shared__ int se[2];
    int g = blockIdx.x >> 2;
    int quarter = blockIdx.x & 3;
    int t = threadIdx.x;
    if (t < 2) {
        int target = g + t;
        int lo = 0, hi = N_NODES;
        while (lo < hi) {
            int mid = (lo + hi) >> 1;
            if (batch[mid] < target) lo = mid + 1; else hi = mid;
        }
        se[t] = lo;
    }
    {
        const float* base = zpart2 + g * DIM + t;
        float acc = 0.f;
#pragma unroll
        for (int p = 0; p < NPART; ++p) acc += base[(size_t)p * (NG * DIM)];
        zr[t] = acc;
    }
    __syncthreads();
    float inv = 1.0f / fmaxf((float)(se[1] - se[0]), 1.0f);
    float acc = 0.f;
#pragma unroll 4
    for (int k = 0; k < DIM; ++k) acc = fmaf(zr[k], W2[k * DIM + t], acc);
    emb[t] = acc * inv + b2[t];
    __syncthreads();
    int a = quarter * 128 + t;
    float s0 = 0.f, s1 = 0.f, s2 = 0.f, s3 = 0.f;
#pragma unroll
    for (int c = 0; c < DIM; c += 4) {
        s0 = fmaf(emb[c + 0], Wf[(c + 0) * ACT + a], s0);
        s1 = fmaf(emb[c + 1], Wf[(c + 1) * ACT + a], s1);
        s2 = fmaf(emb[c + 2], Wf[(c + 2) * ACT + a], s2);
        s3 = fmaf(emb[c + 3], Wf[(c + 3) * ACT + a], s3);
    }
    out[g * ACT + a] = (s0 + s1) + (s2 + s3) + bfv[a];
}

// ---------------- launch ----------------

static inline size_t align256(size_t x) { return (x + 255) & ~(size_t)255; }

extern "C" void kernel_launch(void* const* d_in, const int* in_sizes, int n_in,
                              void* d_out, int out_size, void* d_ws, size_t ws_size,
                              hipStream_t stream) {
    const float* x  = (const float*)d_in[0];
    const int*   ei = (const int*)d_in[1];
    const int*   batch = (const int*)d_in[2];
    const float* W1 = (const float*)d_in[3];
    const float* b1 = (const float*)d_in[4];
    const float* W2 = (const float*)d_in[5];
    const float* b2 = (const float*)d_in[6];
    const float* Wf = (const float*)d_in[7];
    const float* bf = (const float*)d_in[8];
    float* out = (float*)d_out;

    const int* src = ei;
    const int* dst = ei + N_EDGES;

    char* ws = (char*)d_ws;
    size_t off = 0;
    int*   cur     = (int*)(ws + off);   off = align256(off + (size_t)NBUK2 * 4);
    int*   edata_d = (int*)(ws + off);   off = align256(off + (size_t)NBUK * CAPE * 4);
    int*   edata_s = (int*)(ws + off);   off = align256(off + (size_t)NBUK * CAPE * 4);
    int*   ed2     = (int*)(ws + off);   off = align256(off + (size_t)NBUK * CAPE * 4);
    int*   gofs    = (int*)(ws + off);   off = align256(off + (size_t)NBUK * CHUNK * 4);
    float* dis     = (float*)(ws + off); off = align256(off + N_NODES * 4);
    float4* xd     = (float4*)(ws + off); off = align256(off + (size_t)N_NODES * 16);
    float* zpart   = (float*)(ws + off); off = align256(off + (size_t)NBUK * NG * DIM * 4);
    float* zpart2  = (float*)(ws + off); off = align256(off + (size_t)NPART * NG * DIM * 4);

    k_zero<<<2, 1024, 0, stream>>>(cur);
    k_bfill<<<2 * NBLK_E, 1024, 0, stream>>>(src, dst, batch, cur, cur + NBUK, edata_d, edata_s);
    k_indeg<<<NBUK, 512, 0, stream>>>(edata_d, cur, x, dis, xd, ed2, gofs);
    k_aggz<<<GRID_A, 512, 0, stream>>>(ed2, edata_s, cur, cur + NBUK, gofs, batch, dis, xd, W1, b1, zpart);
    k_zred1<<<NPART * NG * DIM / 1024, 256, 0, stream>>>(zpart, zpart2);
    k_poolfinal2<<<NG * 4, 128, 0, stream>>>(zpart2, W2, b2, batch, Wf, bf, out);
}